// Round 2
// baseline (828.442 us; speedup 1.0000x reference)
//
#include <hip/hip_runtime.h>

#define FFT_N 16384
#define FFT_HALF 8192
#define TPB 1024

// reverse 7 base-4 digits (14 bits): bit-reverse 14 bits, then swap adjacent bit pairs
__device__ __forceinline__ int rev4_14(int p) {
  unsigned r = __brev((unsigned)p) >> 18;
  return (int)(((r & 0x1555u) << 1) | ((r & 0x2AAAu) >> 1));
}

extern "C" __global__ void __launch_bounds__(TPB, 1)
fftconv_kernel(const float* __restrict__ x,
               const float* __restrict__ h,
               float* __restrict__ out) {
  extern __shared__ float lds[];
  float* re = lds;            // FFT_N floats
  float* im = lds + FFT_N;    // FFT_N floats
  const int tid = threadIdx.x;
  const long long row = blockIdx.x;
  const float4* xr = (const float4*)(x + row * FFT_HALF);
  const float4* hr = (const float4*)(h + row * FFT_HALF);

  // load z = x + i*h (fp32, float4-vectorized), zero-pad upper half
  #pragma unroll
  for (int it = 0; it < FFT_HALF / (4 * TPB); ++it) {
    int j = tid + it * TPB;           // float4 index
    float4 xv = xr[j];
    float4 hv = hr[j];
    int j4 = j * 4;
    re[j4 + 0] = xv.x; re[j4 + 1] = xv.y; re[j4 + 2] = xv.z; re[j4 + 3] = xv.w;
    im[j4 + 0] = hv.x; im[j4 + 1] = hv.y; im[j4 + 2] = hv.z; im[j4 + 3] = hv.w;
  }
  #pragma unroll
  for (int it = 0; it < FFT_HALF / TPB; ++it) {
    int j = tid + it * TPB + FFT_HALF;
    re[j] = 0.f;
    im[j] = 0.f;
  }
  __syncthreads();

  // ---- forward radix-4 DIF (natural -> base4-digit-reversed), sign e^{-i} ----
  for (int s = 0; s < 7; ++s) {
    const int n = FFT_N >> (2 * s);
    const int q = n >> 2;
    const float wstep = -6.283185307179586f / (float)n;
    for (int b = tid; b < FFT_N / 4; b += TPB) {
      const int j = b & (q - 1);
      const int g = (b ^ j) << 2;          // (b/q)*n
      const int i0 = g + j, i1 = i0 + q, i2 = i1 + q, i3 = i2 + q;
      float a0r = re[i0], a0i = im[i0];
      float a1r = re[i1], a1i = im[i1];
      float a2r = re[i2], a2i = im[i2];
      float a3r = re[i3], a3i = im[i3];
      float t0r = a0r + a2r, t0i = a0i + a2i;
      float t1r = a0r - a2r, t1i = a0i - a2i;
      float t2r = a1r + a3r, t2i = a1i + a3i;
      float t3r = a1r - a3r, t3i = a1i - a3i;
      float y0r = t0r + t2r, y0i = t0i + t2i;   // d=0
      float y1r = t1r + t3i, y1i = t1i - t3r;   // d=1: t1 - i*t3
      float y2r = t0r - t2r, y2i = t0i - t2i;   // d=2
      float y3r = t1r - t3i, y3i = t1i + t3r;   // d=3: t1 + i*t3
      float ang = wstep * (float)j;
      float s1, c1;
      __sincosf(ang, &s1, &c1);
      float c2 = c1 * c1 - s1 * s1, s2 = 2.f * c1 * s1;
      float c3 = c2 * c1 - s2 * s1, s3 = s2 * c1 + c2 * s1;
      re[i0] = y0r;                 im[i0] = y0i;
      re[i1] = y1r * c1 - y1i * s1; im[i1] = y1r * s1 + y1i * c1;
      re[i2] = y2r * c2 - y2i * s2; im[i2] = y2r * s2 + y2i * c2;
      re[i3] = y3r * c3 - y3i * s3; im[i3] = y3r * s3 + y3i * c3;
    }
    __syncthreads();
  }

  // ---- untangle X,H from Z and pointwise S = X*H*2^-28 (digit-reversed storage) ----
  // Iterate over storage positions p with (p&3)<2  <=>  k = rev4(p) in [0, N/2).
  // Partner position pn = rev4(N-k) has (pn&3) in {2,3} -> disjoint, no race.
  const float SC  = 3.7252902984619141e-09f;  // 2^-28  (self-conjugate bins k=0, N/2)
  const float SC4 = 9.3132257461547852e-10f;  // 2^-30  (folds the two 1/2 untangle factors)
  for (int b = tid; b < FFT_HALF; b += TPB) {
    if (b == 0) {
      float x0 = re[0], h0 = im[0];
      re[0] = x0 * h0 * SC; im[0] = 0.f;      // k = 0 bin (position 0)
      float xm = re[2], hm = im[2];
      re[2] = xm * hm * SC; im[2] = 0.f;      // k = N/2 bin lives at position rev4(N/2)=2
    } else {
      int p = ((b >> 1) << 2) | (b & 1);
      int k = rev4_14(p);                      // 0 < k < N/2
      int pn = rev4_14(FFT_N - k);
      float zkr = re[p],  zki = im[p];
      float znr = re[pn], zni = im[pn];
      float Pr = zkr + znr, Pi = zki - zni;    // P = Zk + conj(Z_{N-k}) = 2X
      float Qr = zkr - znr, Qi = zki + zni;    // Q = Zk - conj(Z_{N-k}) = 2iH
      float pqr = Pr * Qr - Pi * Qi;
      float pqi = Pr * Qi + Pi * Qr;
      float Sr = pqi * SC4;                    // S = -i*P*Q/4 * 2^-28
      float Si = -pqr * SC4;
      re[p]  = Sr;  im[p]  = Si;
      re[pn] = Sr;  im[pn] = -Si;              // S_{N-k} = conj(S_k)
    }
  }
  __syncthreads();

  // ---- inverse radix-4 DIT (digit-reversed -> natural), sign e^{+i}, unscaled ----
  for (int s = 0; s < 7; ++s) {
    const int n = 4 << (2 * s);
    const int q = n >> 2;
    const float wstep = 6.283185307179586f / (float)n;
    for (int b = tid; b < FFT_N / 4; b += TPB) {
      const int j = b & (q - 1);
      const int g = (b ^ j) << 2;
      const int i0 = g + j, i1 = i0 + q, i2 = i1 + q, i3 = i2 + q;
      float a0r = re[i0], a0i = im[i0];
      float a1r = re[i1], a1i = im[i1];
      float a2r = re[i2], a2i = im[i2];
      float a3r = re[i3], a3i = im[i3];
      float ang = wstep * (float)j;
      float s1, c1;
      __sincosf(ang, &s1, &c1);
      float c2 = c1 * c1 - s1 * s1, s2 = 2.f * c1 * s1;
      float c3 = c2 * c1 - s2 * s1, s3 = s2 * c1 + c2 * s1;
      float b1r = a1r * c1 - a1i * s1, b1i = a1r * s1 + a1i * c1;
      float b2r = a2r * c2 - a2i * s2, b2i = a2r * s2 + a2i * c2;
      float b3r = a3r * c3 - a3i * s3, b3i = a3r * s3 + a3i * c3;
      float t0r = a0r + b2r, t0i = a0i + b2i;
      float t1r = a0r - b2r, t1i = a0i - b2i;
      float t2r = b1r + b3r, t2i = b1i + b3i;
      float t3r = b1r - b3r, t3i = b1i - b3i;
      re[i0] = t0r + t2r;  im[i0] = t0i + t2i;  // m=0
      re[i1] = t1r - t3i;  im[i1] = t1i + t3r;  // m=1: t1 + i*t3
      re[i2] = t0r - t2r;  im[i2] = t0i - t2i;  // m=2
      re[i3] = t1r + t3i;  im[i3] = t1i - t3r;  // m=3: t1 - i*t3
    }
    __syncthreads();
  }

  // y = Re(first half), already carries the reference's 1/n scaling
  float4* orow = (float4*)(out + row * FFT_HALF);
  #pragma unroll
  for (int it = 0; it < FFT_HALF / (4 * TPB); ++it) {
    int j = tid + it * TPB;           // float4 index
    int j4 = j * 4;
    float4 v;
    v.x = re[j4 + 0]; v.y = re[j4 + 1]; v.z = re[j4 + 2]; v.w = re[j4 + 3];
    orow[j] = v;
  }
}

extern "C" void kernel_launch(void* const* d_in, const int* in_sizes, int n_in,
                              void* d_out, int out_size, void* d_ws, size_t ws_size,
                              hipStream_t stream) {
  const float* x = (const float*)d_in[0];
  const float* h = (const float*)d_in[1];
  float* out = (float*)d_out;
  const int rows = out_size / FFT_HALF;   // 4096
  const size_t lds_bytes = (size_t)(2 * FFT_N) * sizeof(float);  // 128 KiB
  (void)hipFuncSetAttribute((const void*)fftconv_kernel,
                            hipFuncAttributeMaxDynamicSharedMemorySize,
                            (int)lds_bytes);
  hipLaunchKernelGGL(fftconv_kernel, dim3(rows), dim3(TPB), lds_bytes, stream,
                     x, h, out);
}

// Round 3
// 559.428 us; speedup vs baseline: 1.4809x; 1.4809x over previous
//
#include <hip/hip_runtime.h>

#define TPB 1024
#define NFFT 16384
#define LROW 8192

typedef float2 cpx;

// XOR-swizzle on complex index: kills bank conflicts for all stride-4^k rounds.
__device__ __forceinline__ int swz(int p) { return p ^ ((p >> 4) & 15); }

// reverse 7 base-4 digits (14 bits)
__device__ __forceinline__ int rev4_14(int p) {
  unsigned r = __brev((unsigned)p) >> 18;
  return (int)(((r & 0x1555u) << 1) | ((r & 0x2AAAu) >> 1));
}

// hardware sin/cos: input in REVOLUTIONS (v_sin_f32: D = sin(S0*2pi))
__device__ __forceinline__ void sc_rev(float rev, float& c, float& s) {
  s = __builtin_amdgcn_sinf(rev);
  c = __builtin_amdgcn_cosf(rev);
}

__device__ __forceinline__ cpx cmul(cpx a, float c, float s) {
  return make_float2(a.x * c - a.y * s, a.x * s + a.y * c);
}

#define C16 0.923879532511287f
#define S16 0.382683432365090f

// radix-4 DIF core (sign e^{-i}), in place
__device__ __forceinline__ void dif_core(cpx& a0, cpx& a1, cpx& a2, cpx& a3) {
  float t0r = a0.x + a2.x, t0i = a0.y + a2.y;
  float t1r = a0.x - a2.x, t1i = a0.y - a2.y;
  float t2r = a1.x + a3.x, t2i = a1.y + a3.y;
  float t3r = a1.x - a3.x, t3i = a1.y - a3.y;
  a0 = make_float2(t0r + t2r, t0i + t2i);
  a1 = make_float2(t1r + t3i, t1i - t3r);   // t1 - i*t3
  a2 = make_float2(t0r - t2r, t0i - t2i);
  a3 = make_float2(t1r - t3i, t1i + t3r);   // t1 + i*t3
}

// radix-4 DIT core (inputs pre-twiddled, sign e^{+i}), in place
__device__ __forceinline__ void dit_core(cpx& a0, cpx& a1, cpx& a2, cpx& a3) {
  float t0r = a0.x + a2.x, t0i = a0.y + a2.y;
  float t1r = a0.x - a2.x, t1i = a0.y - a2.y;
  float t2r = a1.x + a3.x, t2i = a1.y + a3.y;
  float t3r = a1.x - a3.x, t3i = a1.y - a3.y;
  a0 = make_float2(t0r + t2r, t0i + t2i);
  a1 = make_float2(t1r - t3i, t1i + t3r);   // t1 + i*t3
  a2 = make_float2(t0r - t2r, t0i - t2i);
  a3 = make_float2(t1r + t3i, t1i - t3r);   // t1 - i*t3
}

// ---- forward round A: global -> 2 stages in regs (n=16384, 4096) -> LDS ----
__device__ __forceinline__ void fwd_first(const float* __restrict__ xr,
                                          const float* __restrict__ hr,
                                          cpx* __restrict__ z, int t) {
  cpx X[4][4];  // [e][d], p = t + 1024e + 4096d ; d=2,3 are the zero padding
  #pragma unroll
  for (int e = 0; e < 4; e++) {
    #pragma unroll
    for (int d = 0; d < 2; d++) {
      int p = t + 1024 * e + 4096 * d;
      X[e][d] = make_float2(xr[p], hr[p]);
    }
  }
  // stage n=16384 (q=4096): inputs d=2,3 zero => y0=a0+a1, y1=a0-i a1, y2=a0-a1, y3=a0+i a1
  float c1, s1;
  sc_rev(-(float)t * (1.0f / 16384.0f), c1, s1);
  #pragma unroll
  for (int e = 0; e < 4; e++) {
    if (e) {  // rotate by -2pi/16
      float tc = c1 * C16 + s1 * S16;
      float ts = s1 * C16 - c1 * S16;
      c1 = tc; s1 = ts;
    }
    cpx a0 = X[e][0], a1 = X[e][1];
    cpx y1 = make_float2(a0.x + a1.y, a0.y - a1.x);
    cpx y2 = make_float2(a0.x - a1.x, a0.y - a1.y);
    cpx y3 = make_float2(a0.x - a1.y, a0.y + a1.x);
    float c2 = c1 * c1 - s1 * s1, s2 = 2.f * c1 * s1;
    float c3 = c2 * c1 - s2 * s1, s3 = s2 * c1 + c2 * s1;
    X[e][0] = make_float2(a0.x + a1.x, a0.y + a1.y);
    X[e][1] = cmul(y1, c1, s1);
    X[e][2] = cmul(y2, c2, s2);
    X[e][3] = cmul(y3, c3, s3);
  }
  // stage n=4096 (q=1024): combine over e, twiddle index t
  float cb, sb;
  sc_rev(-(float)t * (1.0f / 4096.0f), cb, sb);
  float cb2 = cb * cb - sb * sb, sb2 = 2.f * cb * sb;
  float cb3 = cb2 * cb - sb2 * sb, sb3 = sb2 * cb + cb2 * sb;
  #pragma unroll
  for (int d = 0; d < 4; d++) {
    dif_core(X[0][d], X[1][d], X[2][d], X[3][d]);
    X[1][d] = cmul(X[1][d], cb, sb);
    X[2][d] = cmul(X[2][d], cb2, sb2);
    X[3][d] = cmul(X[3][d], cb3, sb3);
  }
  #pragma unroll
  for (int e = 0; e < 4; e++)
    #pragma unroll
    for (int d = 0; d < 4; d++)
      z[swz(t + 1024 * e + 4096 * d)] = X[e][d];
}

// ---- generic forward fused pair: stages (n, n/4) ----
template <int n>
__device__ __forceinline__ void fwd_pair(cpx* __restrict__ z, int t) {
  constexpr int q = n >> 2;
  constexpr int qp = n >> 4;
  const int jp = t & (qp - 1);
  const int base = ((t & ~(qp - 1)) << 4) + jp;  // G + jp, G = (t/qp)*n
  cpx X[4][4];
  #pragma unroll
  for (int e = 0; e < 4; e++)
    #pragma unroll
    for (int d = 0; d < 4; d++)
      X[e][d] = z[swz(base + e * qp + d * q)];
  // stage n: combine over d, twiddle idx j = jp + e*qp, w = e^{-2pi i j/n}
  float c1, s1;
  sc_rev(-(float)jp / (float)n, c1, s1);
  #pragma unroll
  for (int e = 0; e < 4; e++) {
    if (e) {
      float tc = c1 * C16 + s1 * S16;
      float ts = s1 * C16 - c1 * S16;
      c1 = tc; s1 = ts;
    }
    dif_core(X[e][0], X[e][1], X[e][2], X[e][3]);
    float c2 = c1 * c1 - s1 * s1, s2 = 2.f * c1 * s1;
    float c3 = c2 * c1 - s2 * s1, s3 = s2 * c1 + c2 * s1;
    X[e][1] = cmul(X[e][1], c1, s1);
    X[e][2] = cmul(X[e][2], c2, s2);
    X[e][3] = cmul(X[e][3], c3, s3);
  }
  // stage n/4: combine over e, twiddle idx jp, w = e^{-2pi i jp/q}
  float cb, sb;
  sc_rev(-(float)jp / (float)q, cb, sb);
  float cb2 = cb * cb - sb * sb, sb2 = 2.f * cb * sb;
  float cb3 = cb2 * cb - sb2 * sb, sb3 = sb2 * cb + cb2 * sb;
  #pragma unroll
  for (int d = 0; d < 4; d++) {
    dif_core(X[0][d], X[1][d], X[2][d], X[3][d]);
    X[1][d] = cmul(X[1][d], cb, sb);
    X[2][d] = cmul(X[2][d], cb2, sb2);
    X[3][d] = cmul(X[3][d], cb3, sb3);
  }
  #pragma unroll
  for (int e = 0; e < 4; e++)
    #pragma unroll
    for (int d = 0; d < 4; d++)
      z[swz(base + e * qp + d * q)] = X[e][d];
}

// ---- forward last stage (n=4, q=1): 4 contiguous butterflies, no twiddles ----
__device__ __forceinline__ void fwd_last(cpx* __restrict__ z, int t) {
  const int base = 16 * t;
  #pragma unroll
  for (int u = 0; u < 4; u++) {
    cpx a0 = z[swz(base + 4 * u + 0)];
    cpx a1 = z[swz(base + 4 * u + 1)];
    cpx a2 = z[swz(base + 4 * u + 2)];
    cpx a3 = z[swz(base + 4 * u + 3)];
    dif_core(a0, a1, a2, a3);
    z[swz(base + 4 * u + 0)] = a0;
    z[swz(base + 4 * u + 1)] = a1;
    z[swz(base + 4 * u + 2)] = a2;
    z[swz(base + 4 * u + 3)] = a3;
  }
}

// ---- untangle + pointwise product (digit-reversed storage) ----
__device__ __forceinline__ void untangle(cpx* __restrict__ z, int t) {
  const float SC = 3.7252902984619141e-09f;   // 2^-28
  const float SC4 = 9.3132257461547852e-10f;  // 2^-30
  #pragma unroll
  for (int it = 0; it < 8; it++) {
    int b = t + it * TPB;
    if (b == 0) {
      cpx z0 = z[0];                      // swz(0)=0, k=0 bin
      z[0] = make_float2(z0.x * z0.y * SC, 0.f);
      cpx zm = z[2];                      // swz(2)=2, k=N/2 bin at position rev4(N/2)=2
      z[2] = make_float2(zm.x * zm.y * SC, 0.f);
    } else {
      int p = ((b >> 1) << 2) | (b & 1);
      int k = rev4_14(p);                 // 0 < k < N/2
      int pn = rev4_14(NFFT - k);
      cpx zk = z[swz(p)];
      cpx zn = z[swz(pn)];
      float Pr = zk.x + zn.x, Pi = zk.y - zn.y;   // 2X
      float Qr = zk.x - zn.x, Qi = zk.y + zn.y;   // 2iH
      float pqr = Pr * Qr - Pi * Qi;
      float pqi = Pr * Qi + Pi * Qr;
      float Sr = pqi * SC4, Si = -pqr * SC4;      // S = -i*P*Q/4 * 2^-28
      z[swz(p)] = make_float2(Sr, Si);
      z[swz(pn)] = make_float2(Sr, -Si);
    }
  }
}

// ---- inverse round A': stages (n=4, n=16), all twiddles are constants ----
__device__ __forceinline__ void inv_first(cpx* __restrict__ z, int t) {
  const int base = 16 * t;
  cpx X[4][4];  // [e][d], p = base + e + 4d
  #pragma unroll
  for (int e = 0; e < 4; e++)
    #pragma unroll
    for (int d = 0; d < 4; d++)
      X[e][d] = z[swz(base + e + 4 * d)];
  // stage n=4 (jA=0, no twiddle): combine over e for each d
  #pragma unroll
  for (int d = 0; d < 4; d++)
    dit_core(X[0][d], X[1][d], X[2][d], X[3][d]);
  // stage n=16: for e-slot m, twiddle inputs d by w^d, w = e^{2pi i m/16}
  dit_core(X[0][0], X[0][1], X[0][2], X[0][3]);
  X[1][1] = cmul(X[1][1], C16, S16);
  X[1][2] = cmul(X[1][2], 0.70710678118655f, 0.70710678118655f);
  X[1][3] = cmul(X[1][3], S16, C16);
  dit_core(X[1][0], X[1][1], X[1][2], X[1][3]);
  X[2][1] = cmul(X[2][1], 0.70710678118655f, 0.70710678118655f);
  X[2][2] = make_float2(-X[2][2].y, X[2][2].x);   // * i
  X[2][3] = cmul(X[2][3], -0.70710678118655f, 0.70710678118655f);
  dit_core(X[2][0], X[2][1], X[2][2], X[2][3]);
  X[3][1] = cmul(X[3][1], S16, C16);
  X[3][2] = cmul(X[3][2], -0.70710678118655f, 0.70710678118655f);
  X[3][3] = cmul(X[3][3], -C16, -S16);
  dit_core(X[3][0], X[3][1], X[3][2], X[3][3]);
  #pragma unroll
  for (int e = 0; e < 4; e++)
    #pragma unroll
    for (int d = 0; d < 4; d++)
      z[swz(base + e + 4 * d)] = X[e][d];
}

// ---- generic inverse fused pair: stages (nA, 4*nA) ----
template <int nA>
__device__ __forceinline__ void inv_pair(cpx* __restrict__ z, int t) {
  constexpr int qA = nA >> 2;
  constexpr int nB = nA << 2;
  const int jA = t & (qA - 1);
  const int base = ((t & ~(qA - 1)) << 4) + jA;  // GB + jA, GB = (t/qA)*nB
  cpx X[4][4];  // [e][d], p = base + e*qA + d*nA
  #pragma unroll
  for (int e = 0; e < 4; e++)
    #pragma unroll
    for (int d = 0; d < 4; d++)
      X[e][d] = z[swz(base + e * qA + d * nA)];
  // stage nA: twiddle inputs e by w^e (w = e^{+2pi i jA/nA}), combine over e per d
  float c1, s1;
  sc_rev((float)jA / (float)nA, c1, s1);
  float c2 = c1 * c1 - s1 * s1, s2 = 2.f * c1 * s1;
  float c3 = c2 * c1 - s2 * s1, s3 = s2 * c1 + c2 * s1;
  #pragma unroll
  for (int d = 0; d < 4; d++) {
    X[1][d] = cmul(X[1][d], c1, s1);
    X[2][d] = cmul(X[2][d], c2, s2);
    X[3][d] = cmul(X[3][d], c3, s3);
    dit_core(X[0][d], X[1][d], X[2][d], X[3][d]);
  }
  // stage nB: for e-slot, angle beta_e = 2pi (jA + e*qA)/nB, twiddle inputs d
  float cb, sb;
  sc_rev((float)jA / (float)nB, cb, sb);
  #pragma unroll
  for (int e = 0; e < 4; e++) {
    if (e) {  // rotate by +2pi/16
      float tc = cb * C16 - sb * S16;
      float ts = sb * C16 + cb * S16;
      cb = tc; sb = ts;
    }
    float cb2 = cb * cb - sb * sb, sb2 = 2.f * cb * sb;
    float cb3 = cb2 * cb - sb2 * sb, sb3 = sb2 * cb + cb2 * sb;
    X[e][1] = cmul(X[e][1], cb, sb);
    X[e][2] = cmul(X[e][2], cb2, sb2);
    X[e][3] = cmul(X[e][3], cb3, sb3);
    dit_core(X[e][0], X[e][1], X[e][2], X[e][3]);
  }
  #pragma unroll
  for (int e = 0; e < 4; e++)
    #pragma unroll
    for (int d = 0; d < 4; d++)
      z[swz(base + e * qA + d * nA)] = X[e][d];
}

// ---- inverse last stage (n=16384): only Re of outputs m=0,1 -> global ----
__device__ __forceinline__ void inv_last_store(const cpx* __restrict__ z,
                                               float* __restrict__ orow, int t) {
  #pragma unroll
  for (int u = 0; u < 4; u++) {
    int j = t + 1024 * u;
    cpx a0 = z[swz(j)];
    cpx a1 = z[swz(j + 4096)];
    cpx a2 = z[swz(j + 8192)];
    cpx a3 = z[swz(j + 12288)];
    float c1, s1;
    sc_rev((float)j * (1.0f / 16384.0f), c1, s1);
    float c2 = c1 * c1 - s1 * s1, s2 = 2.f * c1 * s1;
    float c3 = c2 * c1 - s2 * s1, s3 = s2 * c1 + c2 * s1;
    float b1r = a1.x * c1 - a1.y * s1, b1i = a1.x * s1 + a1.y * c1;
    float b2r = a2.x * c2 - a2.y * s2;
    float b3r = a3.x * c3 - a3.y * s3, b3i = a3.x * s3 + a3.y * c3;
    float t0r = a0.x + b2r, t1r = a0.x - b2r;
    float t2r = b1r + b3r, t3i = b1i - b3i;
    orow[j] = t0r + t2r;             // y[j]
    orow[j + 4096] = t1r - t3i;      // y[j+4096]
  }
}

extern "C" __global__ void __launch_bounds__(TPB, 4)
fftconv_kernel(const float* __restrict__ x, const float* __restrict__ h,
               float* __restrict__ out) {
  extern __shared__ cpx z[];
  const int t = threadIdx.x;
  const long long row = blockIdx.x;
  const float* xr = x + row * LROW;
  const float* hr = h + row * LROW;

  fwd_first(xr, hr, z, t);  __syncthreads();
  fwd_pair<1024>(z, t);     __syncthreads();
  fwd_pair<64>(z, t);       __syncthreads();
  fwd_last(z, t);           __syncthreads();
  untangle(z, t);           __syncthreads();
  inv_first(z, t);          __syncthreads();
  inv_pair<64>(z, t);       __syncthreads();
  inv_pair<1024>(z, t);     __syncthreads();
  inv_last_store(z, out + row * LROW, t);
}

extern "C" void kernel_launch(void* const* d_in, const int* in_sizes, int n_in,
                              void* d_out, int out_size, void* d_ws, size_t ws_size,
                              hipStream_t stream) {
  const float* x = (const float*)d_in[0];
  const float* h = (const float*)d_in[1];
  float* out = (float*)d_out;
  const int rows = out_size / LROW;  // 4096
  const size_t lds_bytes = (size_t)NFFT * sizeof(cpx);  // 128 KiB
  (void)hipFuncSetAttribute((const void*)fftconv_kernel,
                            hipFuncAttributeMaxDynamicSharedMemorySize,
                            (int)lds_bytes);
  hipLaunchKernelGGL(fftconv_kernel, dim3(rows), dim3(TPB), lds_bytes, stream,
                     x, h, out);
}